// Round 7
// baseline (632.990 us; speedup 1.0000x reference)
//
#include <hip/hip_runtime.h>
#include <hip/hip_bf16.h>

#define DIV_UP(a,b) (((a)+(b)-1)/(b))

typedef __attribute__((ext_vector_type(8))) short short8;
typedef __attribute__((ext_vector_type(4))) float floatx4;

// ---------- bf16 helpers (manual, deterministic RNE) ----------
static __device__ __forceinline__ unsigned short f2bf(float v) {
    unsigned u = __builtin_bit_cast(unsigned, v);
    u += 0x7fffu + ((u >> 16) & 1u);
    return (unsigned short)(u >> 16);
}
static __device__ __forceinline__ float bflo(unsigned v) {
    return __builtin_bit_cast(float, v << 16);
}
static __device__ __forceinline__ float bfhi(unsigned v) {
    return __builtin_bit_cast(float, v & 0xffff0000u);
}

// load CPL bf16 -> float
template <int CPL>
static __device__ __forceinline__ void load_bf16v(const unsigned short* p, float* d) {
    if constexpr (CPL == 16) {
        uint4 v = *(const uint4*)p;
        uint4 w = *(const uint4*)(p + 8);
        d[0] = bflo(v.x); d[1] = bfhi(v.x); d[2] = bflo(v.y); d[3] = bfhi(v.y);
        d[4] = bflo(v.z); d[5] = bfhi(v.z); d[6] = bflo(v.w); d[7] = bfhi(v.w);
        d[8] = bflo(w.x); d[9] = bfhi(w.x); d[10] = bflo(w.y); d[11] = bfhi(w.y);
        d[12] = bflo(w.z); d[13] = bfhi(w.z); d[14] = bflo(w.w); d[15] = bfhi(w.w);
    } else if constexpr (CPL == 8) {
        uint4 v = *(const uint4*)p;
        d[0] = bflo(v.x); d[1] = bfhi(v.x);
        d[2] = bflo(v.y); d[3] = bfhi(v.y);
        d[4] = bflo(v.z); d[5] = bfhi(v.z);
        d[6] = bflo(v.w); d[7] = bfhi(v.w);
    } else if constexpr (CPL == 4) {
        uint2 v = *(const uint2*)p;
        d[0] = bflo(v.x); d[1] = bfhi(v.x);
        d[2] = bflo(v.y); d[3] = bfhi(v.y);
    } else if constexpr (CPL == 2) {
        unsigned v = *(const unsigned*)p;
        d[0] = bflo(v); d[1] = bfhi(v);
    } else {
        d[0] = bflo(*p);
    }
}

template <int CPL>
static __device__ __forceinline__ void store_bf16v(unsigned short* p, const float* s) {
    unsigned short tmp[CPL];
#pragma unroll
    for (int c = 0; c < CPL; ++c) tmp[c] = f2bf(s[c]);
    if constexpr (CPL == 16) {
        *(uint4*)p = *(uint4*)tmp;
        *(uint4*)(p + 8) = *(uint4*)(tmp + 8);
    } else if constexpr (CPL == 8) *(uint4*)p = *(uint4*)tmp;
    else if constexpr (CPL == 4) *(ushort4*)p = *(ushort4*)tmp;
    else if constexpr (CPL == 2) *(ushort2*)p = *(ushort2*)tmp;
    else p[0] = tmp[0];
}

// ---------- weight prep ----------
__global__ void cvt_transpose2(const float* __restrict__ Wa, const float* __restrict__ Wb,
                               int K, int Nn, unsigned short* __restrict__ Wt) {
    int id = blockIdx.x * blockDim.x + threadIdx.x;
    int tot = K * Nn;
    if (id >= 2 * tot) return;
    const float* W = (id < tot) ? Wa : Wb;
    unsigned short* dst = Wt + ((id < tot) ? 0 : (size_t)Nn * K);
    int i = (id < tot) ? id : id - tot;
    int k = i % K, n = i / K;
    dst[(size_t)n * K + k] = f2bf(W[(size_t)k * Nn + n]);
}

__global__ void cvt_bf16(const float* __restrict__ in, unsigned short* __restrict__ out, int n) {
    int id = blockIdx.x * blockDim.x + threadIdx.x;
    if (id < n) out[id] = f2bf(in[id]);
}

// ---------- MFMA bf16 GEMM: C[M,Ntot] = A[M,K] @ Bt[Ntot,K]^T ----------
__global__ __launch_bounds__(256) void gemm_mfma(
    const unsigned short* __restrict__ A, const unsigned short* __restrict__ Bt,
    unsigned short* __restrict__ C, int M, int Ntot, int K) {
    constexpr int LDA = 40;
    __shared__ unsigned short As[128 * LDA];
    __shared__ unsigned short Bs[128 * LDA];
    const int tid = threadIdx.x;
    const int m0 = blockIdx.y * 128, n0 = blockIdx.x * 128;
    const int wave = tid >> 6, lane = tid & 63;
    const int wm = (wave >> 1) * 64, wn = (wave & 1) * 64;
    const int r15 = lane & 15, quad = lane >> 4;
    const int sr = tid >> 1, skc = tid & 1;
    floatx4 acc[4][4];
#pragma unroll
    for (int i = 0; i < 4; ++i)
#pragma unroll
        for (int j = 0; j < 4; ++j) acc[i][j] = (floatx4)0.f;

    for (int k0 = 0; k0 < K; k0 += 32) {
        uint4 a0 = make_uint4(0, 0, 0, 0), a1 = make_uint4(0, 0, 0, 0);
        int am = m0 + sr;
        if (am < M) {
            const unsigned short* ap = A + (size_t)am * K + k0 + skc * 16;
            a0 = *(const uint4*)ap;
            a1 = *(const uint4*)(ap + 8);
        }
        const unsigned short* bp = Bt + (size_t)(n0 + sr) * K + k0 + skc * 16;
        uint4 b0 = *(const uint4*)bp;
        uint4 b1 = *(const uint4*)(bp + 8);
        *(uint4*)(&As[sr * LDA + skc * 16]) = a0;
        *(uint4*)(&As[sr * LDA + skc * 16 + 8]) = a1;
        *(uint4*)(&Bs[sr * LDA + skc * 16]) = b0;
        *(uint4*)(&Bs[sr * LDA + skc * 16 + 8]) = b1;
        __syncthreads();
        short8 af[4], bfr[4];
#pragma unroll
        for (int i = 0; i < 4; ++i)
            af[i] = *(const short8*)(&As[(wm + i * 16 + r15) * LDA + quad * 8]);
#pragma unroll
        for (int j = 0; j < 4; ++j)
            bfr[j] = *(const short8*)(&Bs[(wn + j * 16 + r15) * LDA + quad * 8]);
#pragma unroll
        for (int i = 0; i < 4; ++i)
#pragma unroll
            for (int j = 0; j < 4; ++j)
                acc[i][j] = __builtin_amdgcn_mfma_f32_16x16x32_bf16(af[i], bfr[j], acc[i][j], 0, 0, 0);
        __syncthreads();
    }
#pragma unroll
    for (int i = 0; i < 4; ++i)
#pragma unroll
        for (int j = 0; j < 4; ++j)
#pragma unroll
            for (int r = 0; r < 4; ++r) {
                int m = m0 + wm + i * 16 + quad * 4 + r;
                int n = n0 + wn + j * 16 + r15;
                if (m < M) C[(size_t)m * Ntot + n] = f2bf(acc[i][j][r]);
            }
}

// ---------- CSR build for BOTH graphs ----------
__global__ void count2_kernel(const int* __restrict__ dst0, const int* __restrict__ dst1,
                              int E, int N, int* __restrict__ cnt) {
    int e = blockIdx.x * blockDim.x + threadIdx.x;
    if (e < E) atomicAdd(&cnt[dst0[e]], 1);
    else if (e < 2 * E) atomicAdd(&cnt[N + dst1[e - E]], 1);
}

__global__ __launch_bounds__(1024) void scan_kernel(const int* __restrict__ cnt_all, int N,
                                                    int* __restrict__ off_all, int* __restrict__ cur_all) {
    const int* cnt = cnt_all + blockIdx.x * N;
    int* off = off_all + blockIdx.x * (N + 1);
    int* cur = cur_all + blockIdx.x * N;
    __shared__ int part[1024];
    int t = threadIdx.x;
    int per = (N + 1023) >> 10;
    int base = t * per;
    int s = 0;
    for (int i = 0; i < per; ++i) { int idx = base + i; if (idx < N) s += cnt[idx]; }
    part[t] = s;
    __syncthreads();
    for (int d2 = 1; d2 < 1024; d2 <<= 1) {
        int v = (t >= d2) ? part[t - d2] : 0;
        __syncthreads();
        part[t] += v;
        __syncthreads();
    }
    int pre = (t == 0) ? 0 : part[t - 1];
    for (int i = 0; i < per; ++i) {
        int idx = base + i;
        if (idx < N) { off[idx] = pre; cur[idx] = pre; pre += cnt[idx]; }
    }
    if (t == 1023) off[N] = part[1023];
}

__global__ void fill2_kernel(const int* __restrict__ src0, const int* __restrict__ dst0,
                             const int* __restrict__ src1, const int* __restrict__ dst1,
                             int E, int N, int* __restrict__ cur, int2* __restrict__ edges) {
    int e = blockIdx.x * blockDim.x + threadIdx.x;
    if (e < E) {
        int p = atomicAdd(&cur[dst0[e]], 1);
        edges[p] = make_int2(src0[e], e);
    } else if (e < 2 * E) {
        int i = e - E;
        int p = atomicAdd(&cur[N + dst1[i]], 1);
        edges[E + p] = make_int2(src1[i], i);
    }
}

// ---------- K1: per-edge logits (no softmax recurrence) ----------
// Node-walked; NE edges per group share one sweep of We LDS reads.
template <int D, int C, int CPL, bool HASE, int NE>
static __device__ __forceinline__ void logit_edges(
    const unsigned short* __restrict__ xlr, const float* __restrict__ ea,
    const float* wsh, const float (&att_r)[CPL], const float (&xr_r)[CPL],
    const int2* __restrict__ edges, int j, float* __restrict__ logit_s,
    int lane, int c0, int head) {
    constexpr int G = C / CPL;
    constexpr int H = D / C;
    constexpr int QC = CPL / 4;
    int2 e[NE];
#pragma unroll
    for (int n = 0; n < NE; ++n) e[n] = edges[j + n];
    float ev[HASE ? NE : 1][8];
    if constexpr (HASE) {
#pragma unroll
        for (int n = 0; n < NE; ++n) {
            float4 a = ((const float4*)(ea + (size_t)e[n].y * 8))[0];
            float4 b = ((const float4*)(ea + (size_t)e[n].y * 8))[1];
            ev[n][0] = a.x; ev[n][1] = a.y; ev[n][2] = a.z; ev[n][3] = a.w;
            ev[n][4] = b.x; ev[n][5] = b.y; ev[n][6] = b.z; ev[n][7] = b.w;
        }
    }
    float lg[NE];
#pragma unroll
    for (int n = 0; n < NE; ++n) lg[n] = 0.f;
#pragma unroll
    for (int q = 0; q < QC; ++q) {
        const int cq = q * 4;
        float z[NE][4];
#pragma unroll
        for (int n = 0; n < NE; ++n) {
            float xv[4];
            load_bf16v<4>(xlr + (size_t)e[n].x * (2 * D) + c0 + cq, xv);
#pragma unroll
            for (int c = 0; c < 4; ++c) z[n][c] = xv[c] + xr_r[cq + c];
        }
        if constexpr (HASE) {
#pragma unroll
            for (int k = 0; k < 8; ++k) {
                float4 w4 = *(const float4*)(wsh + k * D + c0 + cq);
#pragma unroll
                for (int n = 0; n < NE; ++n) {
                    z[n][0] = fmaf(ev[n][k], w4.x, z[n][0]);
                    z[n][1] = fmaf(ev[n][k], w4.y, z[n][1]);
                    z[n][2] = fmaf(ev[n][k], w4.z, z[n][2]);
                    z[n][3] = fmaf(ev[n][k], w4.w, z[n][3]);
                }
            }
        }
#pragma unroll
        for (int n = 0; n < NE; ++n)
#pragma unroll
            for (int c = 0; c < 4; ++c) {
                float zz = z[n][c] > 0.f ? z[n][c] : 0.2f * z[n][c];
                lg[n] = fmaf(att_r[cq + c], zz, lg[n]);
            }
    }
#pragma unroll
    for (int o = G / 2; o; o >>= 1)
#pragma unroll
        for (int n = 0; n < NE; ++n) lg[n] += __shfl_xor(lg[n], o, 64);
    if ((lane & (G - 1)) == 0)
#pragma unroll
        for (int n = 0; n < NE; ++n) logit_s[(size_t)(j + n) * H + head] = lg[n];
}

template <int D, int C, int CPL, bool HASE>
__global__ __launch_bounds__(256) void logit_k(
    const unsigned short* __restrict__ xlr, const float* __restrict__ ea,
    const float* __restrict__ We, const float* __restrict__ att,
    const int2* __restrict__ edges, const int* __restrict__ off,
    float* __restrict__ logit_s, int N) {
    constexpr int G = C / CPL;
    constexpr int ACT = D / CPL;  // active lanes
    __shared__ float wsh[HASE ? 8 * D : 4];
    if constexpr (HASE) {
        for (int i = threadIdx.x; i < 2 * D; i += 256)
            ((float4*)wsh)[i] = ((const float4*)We)[i];
        __syncthreads();
    }
    const int wid = threadIdx.x >> 6, lane = threadIdx.x & 63;
    if (lane < ACT) {
        const int c0 = lane * CPL;
        const int head = lane / G;
        float att_r[CPL];
#pragma unroll
        for (int c = 0; c < CPL; ++c) att_r[c] = att[c0 + c];
        for (int node = blockIdx.x * 4 + wid; node < N; node += gridDim.x * 4) {
            float xr_r[CPL];
            load_bf16v<CPL>(xlr + (size_t)node * (2 * D) + D + c0, xr_r);
            const int jb = off[node], je = off[node + 1];
            int j = jb;
            for (; j + 4 <= je; j += 4)
                logit_edges<D, C, CPL, HASE, 4>(xlr, ea, wsh, att_r, xr_r, edges, j, logit_s, lane, c0, head);
            for (; j < je; ++j)
                logit_edges<D, C, CPL, HASE, 1>(xlr, ea, wsh, att_r, xr_r, edges, j, logit_s, lane, c0, head);
        }
    }
}

// ---------- K2: per-(node,head) softmax stats ----------
__global__ void stats_k(const float* __restrict__ logit_s, const int* __restrict__ off,
                        float2* __restrict__ minv, int N, int H) {
    int i = blockIdx.x * blockDim.x + threadIdx.x;
    if (i >= N * H) return;
    int node = i / H, h = i - node * H;
    int jb = off[node], je = off[node + 1];
    float m = -3.0e38f;
    for (int j = jb; j < je; ++j) m = fmaxf(m, logit_s[(size_t)j * H + h]);
    float den = 0.f;
    for (int j = jb; j < je; ++j) den += __expf(logit_s[(size_t)j * H + h] - m);
    minv[i] = make_float2(m, 1.f / (den + 1e-16f));
}

// ---------- K3: aggregation (alpha from precomputed stats, no recurrence) ----------
template <int D, int C, int CPL, bool RELU, bool OUTBF16>
__global__ __launch_bounds__(256) void aggr_k(
    const unsigned short* __restrict__ xlr, const float* __restrict__ logit_s,
    const float2* __restrict__ minv, const int2* __restrict__ edges,
    const int* __restrict__ off, const float* __restrict__ bias,
    void* __restrict__ outp, int N) {
    constexpr int G = C / CPL;
    constexpr int ACT = D / CPL;
    constexpr int H = D / C;
    const int wid = threadIdx.x >> 6, lane = threadIdx.x & 63;
    if (lane < ACT) {
        const int c0 = lane * CPL;
        const int head = lane / G;
        float bias_r[CPL];
#pragma unroll
        for (int c = 0; c < CPL; ++c) bias_r[c] = bias[c0 + c];
        for (int node = blockIdx.x * 4 + wid; node < N; node += gridDim.x * 4) {
            float2 mi = minv[(size_t)node * H + head];
            float acc[CPL];
#pragma unroll
            for (int c = 0; c < CPL; ++c) acc[c] = 0.f;
            const int jb = off[node], je = off[node + 1];
            int j = jb;
            for (; j + 2 <= je; j += 2) {
                int2 e0 = edges[j], e1 = edges[j + 1];
                float lg0 = logit_s[(size_t)j * H + head];
                float lg1 = logit_s[(size_t)(j + 1) * H + head];
                float xv0[CPL], xv1[CPL];
                load_bf16v<CPL>(xlr + (size_t)e0.x * (2 * D) + c0, xv0);
                load_bf16v<CPL>(xlr + (size_t)e1.x * (2 * D) + c0, xv1);
                float p0 = __expf(lg0 - mi.x) * mi.y;
                float p1 = __expf(lg1 - mi.x) * mi.y;
#pragma unroll
                for (int c = 0; c < CPL; ++c)
                    acc[c] = fmaf(p0, xv0[c], fmaf(p1, xv1[c], acc[c]));
            }
            if (j < je) {
                int2 e0 = edges[j];
                float lg0 = logit_s[(size_t)j * H + head];
                float xv0[CPL];
                load_bf16v<CPL>(xlr + (size_t)e0.x * (2 * D) + c0, xv0);
                float p0 = __expf(lg0 - mi.x) * mi.y;
#pragma unroll
                for (int c = 0; c < CPL; ++c) acc[c] = fmaf(p0, xv0[c], acc[c]);
            }
            float r[CPL];
#pragma unroll
            for (int c = 0; c < CPL; ++c) {
                r[c] = acc[c] + bias_r[c];
                if constexpr (RELU) r[c] = fmaxf(r[c], 0.f);
            }
            if constexpr (OUTBF16)
                store_bf16v<CPL>((unsigned short*)outp + (size_t)node * D + c0, r);
            else {
                float* out = (float*)outp + (size_t)node * D + c0;
#pragma unroll
                for (int c = 0; c < CPL; c += 4)
                    *(float4*)(out + c) = make_float4(r[c], r[c + 1], r[c + 2], r[c + 3]);
            }
        }
    }
}

// ---------- head: 2-layer MLP on master (last) node of each graph ----------
__global__ void mlp_kernel(const float* __restrict__ h3, const int* __restrict__ nn,
                           const float* __restrict__ Wfc1, const float* __restrict__ bfc1,
                           const float* __restrict__ Wfc2, const float* __restrict__ bfc2,
                           float* __restrict__ out, int G) {
    int g = blockIdx.x, t = threadIdx.x;  // 64 threads
    int s = 0;
    for (int k = 0; k <= g; ++k) s += nn[k];
    const float* row = h3 + (size_t)(s - 1) * 384;
    float z = bfc1[t];
    for (int k = 0; k < 384; ++k) z = fmaf(row[k], Wfc1[k * 64 + t], z);
    z = fmaxf(z, 0.f);
    float v = z * Wfc2[t];
#pragma unroll
    for (int o = 32; o; o >>= 1) v += __shfl_xor(v, o, 64);
    if (t == 0) out[g] = v + bfc2[0];
}

extern "C" void kernel_launch(void* const* d_in, const int* in_sizes, int n_in,
                              void* d_out, int out_size, void* d_ws, size_t ws_size,
                              hipStream_t stream) {
    const float* x    = (const float*)d_in[0];
    const float* ea   = (const float*)d_in[1];
    const float* Wl1  = (const float*)d_in[2];
    const float* Wr1  = (const float*)d_in[3];
    const float* We1  = (const float*)d_in[4];
    const float* att1 = (const float*)d_in[5];
    const float* b1   = (const float*)d_in[6];
    const float* Wl2  = (const float*)d_in[7];
    const float* Wr2  = (const float*)d_in[8];
    const float* We2  = (const float*)d_in[9];
    const float* att2 = (const float*)d_in[10];
    const float* b2   = (const float*)d_in[11];
    const float* Wlp  = (const float*)d_in[12];
    const float* Wrp  = (const float*)d_in[13];
    const float* attp = (const float*)d_in[14];
    const float* bp   = (const float*)d_in[15];
    const float* Wfc1 = (const float*)d_in[16];
    const float* bfc1 = (const float*)d_in[17];
    const float* Wfc2 = (const float*)d_in[18];
    const float* bfc2 = (const float*)d_in[19];
    const int* ei     = (const int*)d_in[20];
    const int* eim    = (const int*)d_in[21];
    const int* nn     = (const int*)d_in[22];

    const int N = in_sizes[0] / 64;   // 20000
    const int E = in_sizes[20] / 2;   // 160000
    const int G = in_sizes[22];       // 100
    const int* src1 = ei,  *dst1 = ei + E;
    const int* srcm = eim, *dstm = eim + E;

    // ---- workspace layout (~165 MB peak) ----
    char* w = (char*)d_ws;
    size_t o = 0;
    auto alloc = [&](size_t b) { size_t r = o; o += (b + 255) & ~(size_t)255; return r; };
    char* R1 = w + alloc((size_t)N * 2048 * 2);
    unsigned short* xlr1 = (unsigned short*)R1;
    unsigned short* xlr3 = (unsigned short*)R1;
    float* h3 = (float*)(R1 + (size_t)N * 768 * 2 + 256);
    unsigned short* h1   = (unsigned short*)(w + alloc((size_t)N * 1024 * 2));
    unsigned short* xlr2 = (unsigned short*)(w + alloc((size_t)N * 512 * 2));
    unsigned short* h2   = (unsigned short*)(w + alloc((size_t)N * 256 * 2));
    unsigned short* xbf  = (unsigned short*)(w + alloc((size_t)N * 64 * 2));
    unsigned short* wt1  = (unsigned short*)(w + alloc((size_t)2048 * 64 * 2));
    unsigned short* wt2  = (unsigned short*)(w + alloc((size_t)512 * 1024 * 2));
    unsigned short* wt3  = (unsigned short*)(w + alloc((size_t)768 * 256 * 2));
    int*  cnt   = (int*)(w + alloc((size_t)2 * N * 4));
    int*  off   = (int*)(w + alloc((size_t)2 * (N + 1) * 4));
    int*  cur   = (int*)(w + alloc((size_t)2 * N * 4));
    int2* edges = (int2*)(w + alloc((size_t)2 * E * 8));
    float*  logit_s = (float*)(w + alloc((size_t)E * 6 * 4));
    float2* minv    = (float2*)(w + alloc((size_t)N * 6 * 8));
    (void)ws_size; (void)n_in; (void)out_size;

    dim3 blk(256);

    // ---- weight prep ----
    cvt_transpose2<<<DIV_UP(2 * 64 * 1024, 256), blk, 0, stream>>>(Wl1, Wr1, 64, 1024, wt1);
    cvt_transpose2<<<DIV_UP(2 * 1024 * 256, 256), blk, 0, stream>>>(Wl2, Wr2, 1024, 256, wt2);
    cvt_transpose2<<<DIV_UP(2 * 256 * 384, 256), blk, 0, stream>>>(Wlp, Wrp, 256, 384, wt3);
    cvt_bf16<<<DIV_UP(N * 64, 256), blk, 0, stream>>>(x, xbf, N * 64);

    // ---- CSR for both graphs ----
    hipMemsetAsync(cnt, 0, (size_t)2 * N * 4, stream);
    count2_kernel<<<DIV_UP(2 * E, 256), blk, 0, stream>>>(dst1, dstm, E, N, cnt);
    scan_kernel<<<2, 1024, 0, stream>>>(cnt, N, off, cur);
    fill2_kernel<<<DIV_UP(2 * E, 256), blk, 0, stream>>>(src1, dst1, srcm, dstm, E, N, cur, edges);
    const int* off3 = off + (N + 1);
    int2* edges3 = edges + E;

    // ---- Layer 1: H=4, C=256, D=1024 — CPL=16, G=16 ----
    gemm_mfma<<<dim3(2048 / 128, DIV_UP(N, 128)), blk, 0, stream>>>(xbf, wt1, xlr1, N, 2048, 64);
    logit_k<1024, 256, 16, true><<<2560, blk, 0, stream>>>(xlr1, ea, We1, att1, edges, off, logit_s, N);
    stats_k<<<DIV_UP(N * 4, 256), blk, 0, stream>>>(logit_s, off, minv, N, 4);
    aggr_k<1024, 256, 16, true, true><<<DIV_UP(N, 4), blk, 0, stream>>>(
        xlr1, logit_s, minv, edges, off, b1, h1, N);

    // ---- Layer 2: H=4, C=64, D=256 — CPL=4, G=16 ----
    gemm_mfma<<<dim3(512 / 128, DIV_UP(N, 128)), blk, 0, stream>>>(h1, wt2, xlr2, N, 512, 1024);
    logit_k<256, 64, 4, true><<<2560, blk, 0, stream>>>(xlr2, ea, We2, att2, edges, off, logit_s, N);
    stats_k<<<DIV_UP(N * 4, 256), blk, 0, stream>>>(logit_s, off, minv, N, 4);
    aggr_k<256, 64, 4, true, true><<<DIV_UP(N, 4), blk, 0, stream>>>(
        xlr2, logit_s, minv, edges, off, b2, h2, N);

    // ---- Layer 3: H=6, C=64, D=384 — CPL=8, G=8, 48 active lanes, fp32 out ----
    gemm_mfma<<<dim3(768 / 128, DIV_UP(N, 128)), blk, 0, stream>>>(h2, wt3, xlr3, N, 768, 256);
    logit_k<384, 64, 8, false><<<2560, blk, 0, stream>>>(xlr3, nullptr, nullptr, attp, edges3, off3, logit_s, N);
    stats_k<<<DIV_UP(N * 6, 256), blk, 0, stream>>>(logit_s, off3, minv, N, 6);
    aggr_k<384, 64, 8, false, false><<<DIV_UP(N, 4), blk, 0, stream>>>(
        xlr3, logit_s, minv, edges3, off3, bp, h3, N);

    // ---- head ----
    mlp_kernel<<<G, 64, 0, stream>>>(h3, nn, Wfc1, bfc1, Wfc2, bfc2, (float*)d_out, G);
}

// Round 8
// 497.738 us; speedup vs baseline: 1.2717x; 1.2717x over previous
//
#include <hip/hip_runtime.h>
#include <hip/hip_bf16.h>

#define DIV_UP(a,b) (((a)+(b)-1)/(b))

typedef __attribute__((ext_vector_type(8))) short short8;
typedef __attribute__((ext_vector_type(4))) float floatx4;

// ---------- bf16 helpers (manual, deterministic RNE) ----------
static __device__ __forceinline__ unsigned short f2bf(float v) {
    unsigned u = __builtin_bit_cast(unsigned, v);
    u += 0x7fffu + ((u >> 16) & 1u);
    return (unsigned short)(u >> 16);
}
static __device__ __forceinline__ float bflo(unsigned v) {
    return __builtin_bit_cast(float, v << 16);
}
static __device__ __forceinline__ float bfhi(unsigned v) {
    return __builtin_bit_cast(float, v & 0xffff0000u);
}

// load CPL bf16 -> float (1 VALU op per channel)
template <int CPL>
static __device__ __forceinline__ void load_bf16v(const unsigned short* p, float* d) {
    if constexpr (CPL == 8) {
        uint4 v = *(const uint4*)p;
        d[0] = bflo(v.x); d[1] = bfhi(v.x);
        d[2] = bflo(v.y); d[3] = bfhi(v.y);
        d[4] = bflo(v.z); d[5] = bfhi(v.z);
        d[6] = bflo(v.w); d[7] = bfhi(v.w);
    } else if constexpr (CPL == 4) {
        uint2 v = *(const uint2*)p;
        d[0] = bflo(v.x); d[1] = bfhi(v.x);
        d[2] = bflo(v.y); d[3] = bfhi(v.y);
    } else if constexpr (CPL == 2) {
        unsigned v = *(const unsigned*)p;
        d[0] = bflo(v); d[1] = bfhi(v);
    } else {
        d[0] = bflo(*p);
    }
}

template <int CPL>
static __device__ __forceinline__ void store_bf16v(unsigned short* p, const float* s) {
    unsigned short tmp[CPL];
#pragma unroll
    for (int c = 0; c < CPL; ++c) tmp[c] = f2bf(s[c]);
    if constexpr (CPL == 8) *(uint4*)p = *(uint4*)tmp;
    else if constexpr (CPL == 4) *(ushort4*)p = *(ushort4*)tmp;
    else if constexpr (CPL == 2) *(ushort2*)p = *(ushort2*)tmp;
    else p[0] = tmp[0];
}

static __device__ __forceinline__ void load_f32x8(const float* p, float* d) {
    float4 a = ((const float4*)p)[0];
    float4 b = ((const float4*)p)[1];
    d[0] = a.x; d[1] = a.y; d[2] = a.z; d[3] = a.w;
    d[4] = b.x; d[5] = b.y; d[6] = b.z; d[7] = b.w;
}

// ---------- DPP group reduction (VALU pipe, not DS) ----------
// quad_perm xor1=0xB1, xor2=0x4E; row_ror:4=0x124, row_ror:8=0x128.
// Valid for aligned groups G in {16,32,64}; result in all lanes of group.
template <int CTRL>
static __device__ __forceinline__ float dpp_mv(float x) {
    int r = __builtin_amdgcn_update_dpp(0, __builtin_bit_cast(int, x), CTRL, 0xF, 0xF, false);
    return __builtin_bit_cast(float, r);
}
template <int G>
static __device__ __forceinline__ float group_reduce(float x) {
    x += dpp_mv<0xB1>(x);   // xor 1 (quad_perm [1,0,3,2])
    x += dpp_mv<0x4E>(x);   // xor 2 (quad_perm [2,3,0,1])
    x += dpp_mv<0x124>(x);  // row_ror:4  -> + next quad
    x += dpp_mv<0x128>(x);  // row_ror:8  -> full 16-row sum in all lanes
    if constexpr (G >= 32) x += __shfl_xor(x, 16, 64);
    if constexpr (G >= 64) x += __shfl_xor(x, 32, 64);
    return x;
}

// ---------- weight prep ----------
__global__ void cvt_transpose2(const float* __restrict__ Wa, const float* __restrict__ Wb,
                               int K, int Nn, unsigned short* __restrict__ Wt) {
    int id = blockIdx.x * blockDim.x + threadIdx.x;
    int tot = K * Nn;
    if (id >= 2 * tot) return;
    const float* W = (id < tot) ? Wa : Wb;
    unsigned short* dst = Wt + ((id < tot) ? 0 : (size_t)Nn * K);
    int i = (id < tot) ? id : id - tot;
    int k = i % K, n = i / K;
    dst[(size_t)n * K + k] = f2bf(W[(size_t)k * Nn + n]);
}

__global__ void cvt_bf16(const float* __restrict__ in, unsigned short* __restrict__ out, int n) {
    int id = blockIdx.x * blockDim.x + threadIdx.x;
    if (id < n) out[id] = f2bf(in[id]);
}

// ---------- MFMA bf16 GEMM: C[M,Ntot] = A[M,K] @ Bt[Ntot,K]^T ----------
__global__ __launch_bounds__(256) void gemm_mfma(
    const unsigned short* __restrict__ A, const unsigned short* __restrict__ Bt,
    unsigned short* __restrict__ C, int M, int Ntot, int K) {
    constexpr int LDA = 40;
    __shared__ unsigned short As[128 * LDA];
    __shared__ unsigned short Bs[128 * LDA];
    const int tid = threadIdx.x;
    const int m0 = blockIdx.y * 128, n0 = blockIdx.x * 128;
    const int wave = tid >> 6, lane = tid & 63;
    const int wm = (wave >> 1) * 64, wn = (wave & 1) * 64;
    const int r15 = lane & 15, quad = lane >> 4;
    const int sr = tid >> 1, skc = tid & 1;
    floatx4 acc[4][4];
#pragma unroll
    for (int i = 0; i < 4; ++i)
#pragma unroll
        for (int j = 0; j < 4; ++j) acc[i][j] = (floatx4)0.f;

    for (int k0 = 0; k0 < K; k0 += 32) {
        uint4 a0 = make_uint4(0, 0, 0, 0), a1 = make_uint4(0, 0, 0, 0);
        int am = m0 + sr;
        if (am < M) {
            const unsigned short* ap = A + (size_t)am * K + k0 + skc * 16;
            a0 = *(const uint4*)ap;
            a1 = *(const uint4*)(ap + 8);
        }
        const unsigned short* bp = Bt + (size_t)(n0 + sr) * K + k0 + skc * 16;
        uint4 b0 = *(const uint4*)bp;
        uint4 b1 = *(const uint4*)(bp + 8);
        *(uint4*)(&As[sr * LDA + skc * 16]) = a0;
        *(uint4*)(&As[sr * LDA + skc * 16 + 8]) = a1;
        *(uint4*)(&Bs[sr * LDA + skc * 16]) = b0;
        *(uint4*)(&Bs[sr * LDA + skc * 16 + 8]) = b1;
        __syncthreads();
        short8 af[4], bfr[4];
#pragma unroll
        for (int i = 0; i < 4; ++i)
            af[i] = *(const short8*)(&As[(wm + i * 16 + r15) * LDA + quad * 8]);
#pragma unroll
        for (int j = 0; j < 4; ++j)
            bfr[j] = *(const short8*)(&Bs[(wn + j * 16 + r15) * LDA + quad * 8]);
#pragma unroll
        for (int i = 0; i < 4; ++i)
#pragma unroll
            for (int j = 0; j < 4; ++j)
                acc[i][j] = __builtin_amdgcn_mfma_f32_16x16x32_bf16(af[i], bfr[j], acc[i][j], 0, 0, 0);
        __syncthreads();
    }
#pragma unroll
    for (int i = 0; i < 4; ++i)
#pragma unroll
        for (int j = 0; j < 4; ++j)
#pragma unroll
            for (int r = 0; r < 4; ++r) {
                int m = m0 + wm + i * 16 + quad * 4 + r;
                int n = n0 + wn + j * 16 + r15;
                if (m < M) C[(size_t)m * Ntot + n] = f2bf(acc[i][j][r]);
            }
}

// ---------- CSR build for BOTH graphs ----------
__global__ void count2_kernel(const int* __restrict__ dst0, const int* __restrict__ dst1,
                              int E, int N, int* __restrict__ cnt) {
    int e = blockIdx.x * blockDim.x + threadIdx.x;
    if (e < E) atomicAdd(&cnt[dst0[e]], 1);
    else if (e < 2 * E) atomicAdd(&cnt[N + dst1[e - E]], 1);
}

__global__ __launch_bounds__(1024) void scan_kernel(const int* __restrict__ cnt_all, int N,
                                                    int* __restrict__ off_all, int* __restrict__ cur_all) {
    const int* cnt = cnt_all + blockIdx.x * N;
    int* off = off_all + blockIdx.x * (N + 1);
    int* cur = cur_all + blockIdx.x * N;
    __shared__ int part[1024];
    int t = threadIdx.x;
    int per = (N + 1023) >> 10;
    int base = t * per;
    int s = 0;
    for (int i = 0; i < per; ++i) { int idx = base + i; if (idx < N) s += cnt[idx]; }
    part[t] = s;
    __syncthreads();
    for (int d2 = 1; d2 < 1024; d2 <<= 1) {
        int v = (t >= d2) ? part[t - d2] : 0;
        __syncthreads();
        part[t] += v;
        __syncthreads();
    }
    int pre = (t == 0) ? 0 : part[t - 1];
    for (int i = 0; i < per; ++i) {
        int idx = base + i;
        if (idx < N) { off[idx] = pre; cur[idx] = pre; pre += cnt[idx]; }
    }
    if (t == 1023) off[N] = part[1023];
}

__global__ void fill2_kernel(const int* __restrict__ src0, const int* __restrict__ dst0,
                             const int* __restrict__ src1, const int* __restrict__ dst1,
                             int E, int N, int* __restrict__ cur, int2* __restrict__ edges) {
    int e = blockIdx.x * blockDim.x + threadIdx.x;
    if (e < E) {
        int p = atomicAdd(&cur[dst0[e]], 1);
        edges[p] = make_int2(src0[e], e);
    } else if (e < 2 * E) {
        int i = e - E;
        int p = atomicAdd(&cur[N + dst1[i]], 1);
        edges[E + p] = make_int2(src1[i], i);
    }
}

// ---------- fused attention for HASE layers: swizzled We in LDS, 2-edge unroll, DPP reduce ----------
// Wave owns CB channels (CPL=CB/64 per lane); aligned G=64*C/CB lane groups own one head.
// We stored swizzled: channel c -> b*CB + q*QP + (cc/CPL)*4 + (cc&3); read (k,q) is
// lane-stride-4 dense -> conflict-free ds_read_b128.
template <int D, int C, int CB, int WPN, bool RELU>
__global__ __launch_bounds__(256) void attn_hase(
    const unsigned short* __restrict__ xlr, const float* __restrict__ ea,
    const float* __restrict__ We, const float* __restrict__ att,
    const int2* __restrict__ edges, const int* __restrict__ off,
    const float* __restrict__ bias, unsigned short* __restrict__ outp, int N) {
    constexpr int CPL = CB / 64;      // 4 or 8
    constexpr int HW = CB / C;        // heads per wave
    constexpr int G = 64 / HW;        // lanes per head group (16 or 32)
    constexpr int NPB = 4 / WPN;      // nodes per block-iteration
    constexpr int QP = CB * 4 / CPL;  // floats per q-plane within a wave block
    __shared__ float wsh[8 * D];
    for (int f4 = threadIdx.x; f4 < 2 * D; f4 += 256) {  // 8*D floats = 2*D float4
        int k = f4 / (D / 4);
        int c = (f4 - k * (D / 4)) * 4;
        int b = c / CB, cc = c - b * CB;
        int ln = cc / CPL, q = (cc % CPL) / 4;
        int dst = k * (D / 4) + (b * CB + q * QP + ln * 4) / 4;
        ((float4*)wsh)[dst] = ((const float4*)We)[f4];
    }
    __syncthreads();

    const int wid = threadIdx.x >> 6, lane = threadIdx.x & 63;
    const int wv = wid % WPN, wn = wid / WPN;
    const int c0 = wv * CB + lane * CPL;
    const float* wb = wsh + wv * CB + lane * 4;  // + k*D + q*QP per read

    float att_r[CPL], bias_r[CPL];
#pragma unroll
    for (int c = 0; c < CPL; ++c) { att_r[c] = att[c0 + c]; bias_r[c] = bias[c0 + c]; }

    for (int node = blockIdx.x * NPB + wn; node < N; node += gridDim.x * NPB) {
        float xr_r[CPL];
        load_bf16v<CPL>(xlr + (size_t)node * (2 * D) + D + c0, xr_r);
        float m = -1e30f, l = 0.f, acc[CPL];
#pragma unroll
        for (int c = 0; c < CPL; ++c) acc[c] = 0.f;

        const int jb = off[node], je = off[node + 1];
        int j = jb;
        for (; j + 2 <= je; j += 2) {
            int2 e0 = edges[j], e1 = edges[j + 1];
            float ev0[8], ev1[8];
            load_f32x8(ea + (size_t)e0.y * 8, ev0);
            load_f32x8(ea + (size_t)e1.y * 8, ev1);
            float xv0[CPL], xv1[CPL];
            load_bf16v<CPL>(xlr + (size_t)e0.x * (2 * D) + c0, xv0);
            load_bf16v<CPL>(xlr + (size_t)e1.x * (2 * D) + c0, xv1);
            float z0[CPL], z1[CPL];
#pragma unroll
            for (int c = 0; c < CPL; ++c) {
                z0[c] = xv0[c] + xr_r[c];
                z1[c] = xv1[c] + xr_r[c];
            }
#pragma unroll
            for (int k = 0; k < 8; ++k) {
#pragma unroll
                for (int q = 0; q < CPL / 4; ++q) {
                    float4 w4 = *(const float4*)(wb + k * D + q * QP);
                    z0[q * 4 + 0] = fmaf(ev0[k], w4.x, z0[q * 4 + 0]);
                    z0[q * 4 + 1] = fmaf(ev0[k], w4.y, z0[q * 4 + 1]);
                    z0[q * 4 + 2] = fmaf(ev0[k], w4.z, z0[q * 4 + 2]);
                    z0[q * 4 + 3] = fmaf(ev0[k], w4.w, z0[q * 4 + 3]);
                    z1[q * 4 + 0] = fmaf(ev1[k], w4.x, z1[q * 4 + 0]);
                    z1[q * 4 + 1] = fmaf(ev1[k], w4.y, z1[q * 4 + 1]);
                    z1[q * 4 + 2] = fmaf(ev1[k], w4.z, z1[q * 4 + 2]);
                    z1[q * 4 + 3] = fmaf(ev1[k], w4.w, z1[q * 4 + 3]);
                }
            }
            float lg0 = 0.f, lg1 = 0.f;
#pragma unroll
            for (int c = 0; c < CPL; ++c) {
                float a0 = z0[c] > 0.f ? z0[c] : 0.2f * z0[c];
                float a1 = z1[c] > 0.f ? z1[c] : 0.2f * z1[c];
                lg0 = fmaf(att_r[c], a0, lg0);
                lg1 = fmaf(att_r[c], a1, lg1);
            }
            lg0 = group_reduce<G>(lg0);
            lg1 = group_reduce<G>(lg1);
            float mn = fmaxf(m, fmaxf(lg0, lg1));
            float sc = __expf(m - mn);
            float p0 = __expf(lg0 - mn);
            float p1 = __expf(lg1 - mn);
            m = mn;
            l = fmaf(l, sc, p0 + p1);
#pragma unroll
            for (int c = 0; c < CPL; ++c)
                acc[c] = fmaf(acc[c], sc, fmaf(p0, xv0[c], p1 * xv1[c]));
        }
        if (j < je) {  // tail edge
            int2 e0 = edges[j];
            float ev0[8], xv0[CPL];
            load_f32x8(ea + (size_t)e0.y * 8, ev0);
            load_bf16v<CPL>(xlr + (size_t)e0.x * (2 * D) + c0, xv0);
            float z0[CPL];
#pragma unroll
            for (int c = 0; c < CPL; ++c) z0[c] = xv0[c] + xr_r[c];
#pragma unroll
            for (int k = 0; k < 8; ++k) {
#pragma unroll
                for (int q = 0; q < CPL / 4; ++q) {
                    float4 w4 = *(const float4*)(wb + k * D + q * QP);
                    z0[q * 4 + 0] = fmaf(ev0[k], w4.x, z0[q * 4 + 0]);
                    z0[q * 4 + 1] = fmaf(ev0[k], w4.y, z0[q * 4 + 1]);
                    z0[q * 4 + 2] = fmaf(ev0[k], w4.z, z0[q * 4 + 2]);
                    z0[q * 4 + 3] = fmaf(ev0[k], w4.w, z0[q * 4 + 3]);
                }
            }
            float lg0 = 0.f;
#pragma unroll
            for (int c = 0; c < CPL; ++c) {
                float a0 = z0[c] > 0.f ? z0[c] : 0.2f * z0[c];
                lg0 = fmaf(att_r[c], a0, lg0);
            }
            lg0 = group_reduce<G>(lg0);
            float mn = fmaxf(m, lg0);
            float sc = __expf(m - mn);
            float p0 = __expf(lg0 - mn);
            m = mn;
            l = fmaf(l, sc, p0);
#pragma unroll
            for (int c = 0; c < CPL; ++c) acc[c] = fmaf(acc[c], sc, p0 * xv0[c]);
        }

        float inv = 1.f / (l + 1e-16f);
        float r[CPL];
#pragma unroll
        for (int c = 0; c < CPL; ++c) {
            r[c] = fmaf(acc[c], inv, bias_r[c]);
            if constexpr (RELU) r[c] = fmaxf(r[c], 0.f);
        }
        store_bf16v<CPL>(outp + (size_t)node * D + c0, r);
    }
}

// ---------- fused attention, no edge_attr (layer 3), DPP reduce ----------
template <int D, int C, int CB, bool RELU>
static __device__ __forceinline__ void attn_wave3(
    const unsigned short* __restrict__ xlr, const float* __restrict__ att,
    const int2* __restrict__ edges, int jb, int je,
    const float* __restrict__ bias, float* __restrict__ outp,
    int node, int cb, int lane) {
    constexpr int CPL = CB / 64;
    constexpr int HW = CB / C;
    constexpr int G = 64 / HW;
    const int c0 = cb + lane * CPL;

    float xr_r[CPL], att_r[CPL];
    load_bf16v<CPL>(xlr + (size_t)node * (2 * D) + D + c0, xr_r);
#pragma unroll
    for (int c = 0; c < CPL; ++c) att_r[c] = att[c0 + c];

    float m = -1e30f, l = 0.f, acc[CPL];
#pragma unroll
    for (int c = 0; c < CPL; ++c) acc[c] = 0.f;

    int j = jb;
    for (; j + 2 <= je; j += 2) {
        int2 e0 = edges[j], e1 = edges[j + 1];
        float xv0[CPL], xv1[CPL];
        load_bf16v<CPL>(xlr + (size_t)e0.x * (2 * D) + c0, xv0);
        load_bf16v<CPL>(xlr + (size_t)e1.x * (2 * D) + c0, xv1);
        float lg0 = 0.f, lg1 = 0.f;
#pragma unroll
        for (int c = 0; c < CPL; ++c) {
            float z0 = xv0[c] + xr_r[c];
            float z1 = xv1[c] + xr_r[c];
            z0 = z0 > 0.f ? z0 : 0.2f * z0;
            z1 = z1 > 0.f ? z1 : 0.2f * z1;
            lg0 = fmaf(att_r[c], z0, lg0);
            lg1 = fmaf(att_r[c], z1, lg1);
        }
        lg0 = group_reduce<G>(lg0);
        lg1 = group_reduce<G>(lg1);
        float mn = fmaxf(m, fmaxf(lg0, lg1));
        float sc = __expf(m - mn);
        float p0 = __expf(lg0 - mn);
        float p1 = __expf(lg1 - mn);
        m = mn;
        l = fmaf(l, sc, p0 + p1);
#pragma unroll
        for (int c = 0; c < CPL; ++c)
            acc[c] = fmaf(acc[c], sc, fmaf(p0, xv0[c], p1 * xv1[c]));
    }
    if (j < je) {
        int2 e0 = edges[j];
        float xv0[CPL];
        load_bf16v<CPL>(xlr + (size_t)e0.x * (2 * D) + c0, xv0);
        float lg0 = 0.f;
#pragma unroll
        for (int c = 0; c < CPL; ++c) {
            float z = xv0[c] + xr_r[c];
            z = z > 0.f ? z : 0.2f * z;
            lg0 = fmaf(att_r[c], z, lg0);
        }
        lg0 = group_reduce<G>(lg0);
        float mn = fmaxf(m, lg0);
        float sc = __expf(m - mn);
        float p0 = __expf(lg0 - mn);
        m = mn;
        l = fmaf(l, sc, p0);
#pragma unroll
        for (int c = 0; c < CPL; ++c) acc[c] = fmaf(acc[c], sc, p0 * xv0[c]);
    }

    float inv = 1.f / (l + 1e-16f);
    float* out = outp + (size_t)node * D + c0;
    float tmp[CPL];
#pragma unroll
    for (int c = 0; c < CPL; ++c) {
        float r = fmaf(acc[c], inv, bias[c0 + c]);
        if constexpr (RELU) r = fmaxf(r, 0.f);
        tmp[c] = r;
    }
    if constexpr (CPL == 4) *(float4*)out = *(float4*)tmp;
    else if constexpr (CPL == 2) *(float2*)out = *(float2*)tmp;
    else out[0] = tmp[0];
}

template <int D, int C, int CB0, int CB1, bool RELU>
__global__ __launch_bounds__(256) void attn_noe(
    const unsigned short* __restrict__ xlr, const float* __restrict__ att,
    const int2* __restrict__ edges, const int* __restrict__ off,
    const float* __restrict__ bias, float* __restrict__ outp, int N) {
    const int wid = threadIdx.x >> 6, lane = threadIdx.x & 63;
    const int gw = blockIdx.x * 4 + wid;
    const int node = gw >> 1, wv = gw & 1;
    if (node >= N) return;
    const int jb = off[node], je = off[node + 1];
    if (wv == 0)
        attn_wave3<D, C, CB0, RELU>(xlr, att, edges, jb, je, bias, outp, node, 0, lane);
    else
        attn_wave3<D, C, CB1, RELU>(xlr, att, edges, jb, je, bias, outp, node, CB0, lane);
}

// ---------- head: 2-layer MLP on master (last) node of each graph ----------
__global__ void mlp_kernel(const float* __restrict__ h3, const int* __restrict__ nn,
                           const float* __restrict__ Wfc1, const float* __restrict__ bfc1,
                           const float* __restrict__ Wfc2, const float* __restrict__ bfc2,
                           float* __restrict__ out, int G) {
    int g = blockIdx.x, t = threadIdx.x;  // 64 threads
    int s = 0;
    for (int k = 0; k <= g; ++k) s += nn[k];
    const float* row = h3 + (size_t)(s - 1) * 384;
    float z = bfc1[t];
    for (int k = 0; k < 384; ++k) z = fmaf(row[k], Wfc1[k * 64 + t], z);
    z = fmaxf(z, 0.f);
    float v = z * Wfc2[t];
#pragma unroll
    for (int o = 32; o; o >>= 1) v += __shfl_xor(v, o, 64);
    if (t == 0) out[g] = v + bfc2[0];
}

extern "C" void kernel_launch(void* const* d_in, const int* in_sizes, int n_in,
                              void* d_out, int out_size, void* d_ws, size_t ws_size,
                              hipStream_t stream) {
    const float* x    = (const float*)d_in[0];
    const float* ea   = (const float*)d_in[1];
    const float* Wl1  = (const float*)d_in[2];
    const float* Wr1  = (const float*)d_in[3];
    const float* We1  = (const float*)d_in[4];
    const float* att1 = (const float*)d_in[5];
    const float* b1   = (const float*)d_in[6];
    const float* Wl2  = (const float*)d_in[7];
    const float* Wr2  = (const float*)d_in[8];
    const float* We2  = (const float*)d_in[9];
    const float* att2 = (const float*)d_in[10];
    const float* b2   = (const float*)d_in[11];
    const float* Wlp  = (const float*)d_in[12];
    const float* Wrp  = (const float*)d_in[13];
    const float* attp = (const float*)d_in[14];
    const float* bp   = (const float*)d_in[15];
    const float* Wfc1 = (const float*)d_in[16];
    const float* bfc1 = (const float*)d_in[17];
    const float* Wfc2 = (const float*)d_in[18];
    const float* bfc2 = (const float*)d_in[19];
    const int* ei     = (const int*)d_in[20];
    const int* eim    = (const int*)d_in[21];
    const int* nn     = (const int*)d_in[22];

    const int N = in_sizes[0] / 64;   // 20000
    const int E = in_sizes[20] / 2;   // 160000
    const int G = in_sizes[22];       // 100
    const int* src1 = ei,  *dst1 = ei + E;
    const int* srcm = eim, *dstm = eim + E;

    // ---- workspace layout (~160 MB peak) ----
    char* w = (char*)d_ws;
    size_t o = 0;
    auto alloc = [&](size_t b) { size_t r = o; o += (b + 255) & ~(size_t)255; return r; };
    char* R1 = w + alloc((size_t)N * 2048 * 2);
    unsigned short* xlr1 = (unsigned short*)R1;
    unsigned short* xlr3 = (unsigned short*)R1;
    float* h3 = (float*)(R1 + (size_t)N * 768 * 2 + 256);
    unsigned short* h1   = (unsigned short*)(w + alloc((size_t)N * 1024 * 2));
    unsigned short* xlr2 = (unsigned short*)(w + alloc((size_t)N * 512 * 2));
    unsigned short* h2   = (unsigned short*)(w + alloc((size_t)N * 256 * 2));
    unsigned short* xbf  = (unsigned short*)(w + alloc((size_t)N * 64 * 2));
    unsigned short* wt1  = (unsigned short*)(w + alloc((size_t)2048 * 64 * 2));
    unsigned short* wt2  = (unsigned short*)(w + alloc((size_t)512 * 1024 * 2));
    unsigned short* wt3  = (unsigned short*)(w + alloc((size_t)768 * 256 * 2));
    int*  cnt   = (int*)(w + alloc((size_t)2 * N * 4));
    int*  off   = (int*)(w + alloc((size_t)2 * (N + 1) * 4));
    int*  cur   = (int*)(w + alloc((size_t)2 * N * 4));
    int2* edges = (int2*)(w + alloc((size_t)2 * E * 8 + 4096));
    (void)ws_size; (void)n_in; (void)out_size;

    dim3 blk(256);

    // ---- weight prep ----
    cvt_transpose2<<<DIV_UP(2 * 64 * 1024, 256), blk, 0, stream>>>(Wl1, Wr1, 64, 1024, wt1);
    cvt_transpose2<<<DIV_UP(2 * 1024 * 256, 256), blk, 0, stream>>>(Wl2, Wr2, 1024, 256, wt2);
    cvt_transpose2<<<DIV_UP(2 * 256 * 384, 256), blk, 0, stream>>>(Wlp, Wrp, 256, 384, wt3);
    cvt_bf16<<<DIV_UP(N * 64, 256), blk, 0, stream>>>(x, xbf, N * 64);

    // ---- CSR for both graphs ----
    hipMemsetAsync(cnt, 0, (size_t)2 * N * 4, stream);
    count2_kernel<<<DIV_UP(2 * E, 256), blk, 0, stream>>>(dst1, dstm, E, N, cnt);
    scan_kernel<<<2, 1024, 0, stream>>>(cnt, N, off, cur);
    fill2_kernel<<<DIV_UP(2 * E, 256), blk, 0, stream>>>(src1, dst1, srcm, dstm, E, N, cur, edges);
    const int* off3 = off + (N + 1);
    int2* edges3 = edges + E;

    // ---- Layer 1: H=4, C=256, D=1024 — 2 waves/node, CPL=8, G=32, swizzled We ----
    gemm_mfma<<<dim3(2048 / 128, DIV_UP(N, 128)), blk, 0, stream>>>(xbf, wt1, xlr1, N, 2048, 64);
    attn_hase<1024, 256, 512, 2, true><<<2560, blk, 0, stream>>>(
        xlr1, ea, We1, att1, edges, off, b1, h1, N);

    // ---- Layer 2: H=4, C=64, D=256 — 1 wave/node, CPL=4, G=16 ----
    gemm_mfma<<<dim3(512 / 128, DIV_UP(N, 128)), blk, 0, stream>>>(h1, wt2, xlr2, N, 512, 1024);
    attn_hase<256, 64, 256, 1, true><<<1280, blk, 0, stream>>>(
        xlr2, ea, We2, att2, edges, off, b2, h2, N);

    // ---- Layer 3: H=6, C=64, D=384 — 2 waves/node (roles 256/128), fp32 out ----
    gemm_mfma<<<dim3(768 / 128, DIV_UP(N, 128)), blk, 0, stream>>>(h2, wt3, xlr3, N, 768, 256);
    attn_noe<384, 64, 256, 128, false><<<DIV_UP(N, 2), blk, 0, stream>>>(
        xlr3, attp, edges3, off3, bp, h3, N);

    // ---- head ----
    mlp_kernel<<<G, 64, 0, stream>>>(h3, nn, Wfc1, bfc1, Wfc2, bfc2, (float*)d_out, G);
}

// Round 9
// 423.513 us; speedup vs baseline: 1.4946x; 1.1753x over previous
//
#include <hip/hip_runtime.h>
#include <hip/hip_bf16.h>

#define DIV_UP(a,b) (((a)+(b)-1)/(b))

typedef __attribute__((ext_vector_type(8))) short short8;
typedef __attribute__((ext_vector_type(4))) float floatx4;

// ---------- bf16 helpers (manual, deterministic RNE) ----------
static __device__ __forceinline__ unsigned short f2bf(float v) {
    unsigned u = __builtin_bit_cast(unsigned, v);
    u += 0x7fffu + ((u >> 16) & 1u);
    return (unsigned short)(u >> 16);
}
static __device__ __forceinline__ float bflo(unsigned v) {
    return __builtin_bit_cast(float, v << 16);
}
static __device__ __forceinline__ float bfhi(unsigned v) {
    return __builtin_bit_cast(float, v & 0xffff0000u);
}

template <int CPL>
static __device__ __forceinline__ void load_bf16v(const unsigned short* p, float* d) {
    if constexpr (CPL == 8) {
        uint4 v = *(const uint4*)p;
        d[0] = bflo(v.x); d[1] = bfhi(v.x);
        d[2] = bflo(v.y); d[3] = bfhi(v.y);
        d[4] = bflo(v.z); d[5] = bfhi(v.z);
        d[6] = bflo(v.w); d[7] = bfhi(v.w);
    } else if constexpr (CPL == 4) {
        uint2 v = *(const uint2*)p;
        d[0] = bflo(v.x); d[1] = bfhi(v.x);
        d[2] = bflo(v.y); d[3] = bfhi(v.y);
    } else if constexpr (CPL == 2) {
        unsigned v = *(const unsigned*)p;
        d[0] = bflo(v); d[1] = bfhi(v);
    } else {
        d[0] = bflo(*p);
    }
}

template <int CPL>
static __device__ __forceinline__ void store_bf16v(unsigned short* p, const float* s) {
    unsigned short tmp[CPL];
#pragma unroll
    for (int c = 0; c < CPL; ++c) tmp[c] = f2bf(s[c]);
    if constexpr (CPL == 8) *(uint4*)p = *(uint4*)tmp;
    else if constexpr (CPL == 4) *(ushort4*)p = *(ushort4*)tmp;
    else if constexpr (CPL == 2) *(ushort2*)p = *(ushort2*)tmp;
    else p[0] = tmp[0];
}

// ---------- DPP group reduction (VALU pipe, not DS) ----------
template <int CTRL>
static __device__ __forceinline__ float dpp_mv(float x) {
    int r = __builtin_amdgcn_update_dpp(0, __builtin_bit_cast(int, x), CTRL, 0xF, 0xF, false);
    return __builtin_bit_cast(float, r);
}
template <int G>
static __device__ __forceinline__ float group_reduce(float x) {
    x += dpp_mv<0xB1>(x);   // xor 1
    x += dpp_mv<0x4E>(x);   // xor 2
    x += dpp_mv<0x124>(x);  // row_ror:4
    x += dpp_mv<0x128>(x);  // row_ror:8 -> 16-lane sum
    if constexpr (G >= 32) x += __shfl_xor(x, 16, 64);
    if constexpr (G >= 64) x += __shfl_xor(x, 32, 64);
    return x;
}

// ---------- merged weight prep: 3 transposed pairs + x->bf16 ----------
static __device__ __forceinline__ void tr_pair(const float* Wa, const float* Wb, int K, int Nn,
                                               unsigned short* Wt, int i) {
    int tot = K * Nn;
    const float* W = (i < tot) ? Wa : Wb;
    unsigned short* dst = Wt + ((i < tot) ? 0 : (size_t)Nn * K);
    int ii = (i < tot) ? i : i - tot;
    int k = ii % K, n = ii / K;
    dst[(size_t)n * K + k] = f2bf(W[(size_t)k * Nn + n]);
}

__global__ void prep_all(const float* __restrict__ x,
                         const float* __restrict__ Wl1, const float* __restrict__ Wr1,
                         const float* __restrict__ Wl2, const float* __restrict__ Wr2,
                         const float* __restrict__ Wlp, const float* __restrict__ Wrp,
                         unsigned short* __restrict__ xbf,
                         unsigned short* __restrict__ wt1, unsigned short* __restrict__ wt2,
                         unsigned short* __restrict__ wt3, int N) {
    const int S1 = 2 * 64 * 1024, S2 = 2 * 1024 * 256, S3 = 2 * 256 * 384;
    int id = blockIdx.x * blockDim.x + threadIdx.x;
    if (id < S1) tr_pair(Wl1, Wr1, 64, 1024, wt1, id);
    else if (id < S1 + S2) tr_pair(Wl2, Wr2, 1024, 256, wt2, id - S1);
    else if (id < S1 + S2 + S3) tr_pair(Wlp, Wrp, 256, 384, wt3, id - S1 - S2);
    else {
        int i = id - S1 - S2 - S3;
        if (i < N * 64) xbf[i] = f2bf(x[i]);
    }
}

// ---------- MFMA bf16 GEMM: C[M,Ntot] = A[M,K] @ Bt[Ntot,K]^T ----------
__global__ __launch_bounds__(256) void gemm_mfma(
    const unsigned short* __restrict__ A, const unsigned short* __restrict__ Bt,
    unsigned short* __restrict__ C, int M, int Ntot, int K) {
    constexpr int LDA = 40;
    __shared__ unsigned short As[128 * LDA];
    __shared__ unsigned short Bs[128 * LDA];
    const int tid = threadIdx.x;
    const int m0 = blockIdx.y * 128, n0 = blockIdx.x * 128;
    const int wave = tid >> 6, lane = tid & 63;
    const int wm = (wave >> 1) * 64, wn = (wave & 1) * 64;
    const int r15 = lane & 15, quad = lane >> 4;
    const int sr = tid >> 1, skc = tid & 1;
    floatx4 acc[4][4];
#pragma unroll
    for (int i = 0; i < 4; ++i)
#pragma unroll
        for (int j = 0; j < 4; ++j) acc[i][j] = (floatx4)0.f;

    for (int k0 = 0; k0 < K; k0 += 32) {
        uint4 a0 = make_uint4(0, 0, 0, 0), a1 = make_uint4(0, 0, 0, 0);
        int am = m0 + sr;
        if (am < M) {
            const unsigned short* ap = A + (size_t)am * K + k0 + skc * 16;
            a0 = *(const uint4*)ap;
            a1 = *(const uint4*)(ap + 8);
        }
        const unsigned short* bp = Bt + (size_t)(n0 + sr) * K + k0 + skc * 16;
        uint4 b0 = *(const uint4*)bp;
        uint4 b1 = *(const uint4*)(bp + 8);
        *(uint4*)(&As[sr * LDA + skc * 16]) = a0;
        *(uint4*)(&As[sr * LDA + skc * 16 + 8]) = a1;
        *(uint4*)(&Bs[sr * LDA + skc * 16]) = b0;
        *(uint4*)(&Bs[sr * LDA + skc * 16 + 8]) = b1;
        __syncthreads();
        short8 af[4], bfr[4];
#pragma unroll
        for (int i = 0; i < 4; ++i)
            af[i] = *(const short8*)(&As[(wm + i * 16 + r15) * LDA + quad * 8]);
#pragma unroll
        for (int j = 0; j < 4; ++j)
            bfr[j] = *(const short8*)(&Bs[(wn + j * 16 + r15) * LDA + quad * 8]);
#pragma unroll
        for (int i = 0; i < 4; ++i)
#pragma unroll
            for (int j = 0; j < 4; ++j)
                acc[i][j] = __builtin_amdgcn_mfma_f32_16x16x32_bf16(af[i], bfr[j], acc[i][j], 0, 0, 0);
        __syncthreads();
    }
#pragma unroll
    for (int i = 0; i < 4; ++i)
#pragma unroll
        for (int j = 0; j < 4; ++j)
#pragma unroll
            for (int r = 0; r < 4; ++r) {
                int m = m0 + wm + i * 16 + quad * 4 + r;
                int n = n0 + wn + j * 16 + r15;
                if (m < M) C[(size_t)m * Ntot + n] = f2bf(acc[i][j][r]);
            }
}

// ---------- CSR build for BOTH graphs ----------
__global__ void count2_kernel(const int* __restrict__ dst0, const int* __restrict__ dst1,
                              int E, int N, int* __restrict__ cnt) {
    int e = blockIdx.x * blockDim.x + threadIdx.x;
    if (e < E) atomicAdd(&cnt[dst0[e]], 1);
    else if (e < 2 * E) atomicAdd(&cnt[N + dst1[e - E]], 1);
}

__global__ __launch_bounds__(1024) void scan_kernel(const int* __restrict__ cnt_all, int N,
                                                    int* __restrict__ off_all, int* __restrict__ cur_all) {
    const int* cnt = cnt_all + blockIdx.x * N;
    int* off = off_all + blockIdx.x * (N + 1);
    int* cur = cur_all + blockIdx.x * N;
    __shared__ int part[1024];
    int t = threadIdx.x;
    int per = (N + 1023) >> 10;
    int base = t * per;
    int s = 0;
    for (int i = 0; i < per; ++i) { int idx = base + i; if (idx < N) s += cnt[idx]; }
    part[t] = s;
    __syncthreads();
    for (int d2 = 1; d2 < 1024; d2 <<= 1) {
        int v = (t >= d2) ? part[t - d2] : 0;
        __syncthreads();
        part[t] += v;
        __syncthreads();
    }
    int pre = (t == 0) ? 0 : part[t - 1];
    for (int i = 0; i < per; ++i) {
        int idx = base + i;
        if (idx < N) { off[idx] = pre; cur[idx] = pre; pre += cnt[idx]; }
    }
    if (t == 1023) off[N] = part[1023];
}

__global__ void fill2_kernel(const int* __restrict__ src0, const int* __restrict__ dst0,
                             const int* __restrict__ src1, const int* __restrict__ dst1,
                             int E, int N, int* __restrict__ cur, int2* __restrict__ edges) {
    int e = blockIdx.x * blockDim.x + threadIdx.x;
    if (e < E) {
        int p = atomicAdd(&cur[dst0[e]], 1);
        edges[p] = make_int2(src0[e], e);
    } else if (e < 2 * E) {
        int i = e - E;
        int p = atomicAdd(&cur[N + dst1[i]], 1);
        edges[E + p] = make_int2(src1[i], i);
    }
}

// ---------- fused attention (HASE): swizzled We in LDS, NE-edge groups, scalar edge meta ----------
template <int D, int CPL, int QP, int G, int NE>
static __device__ __forceinline__ void hase_group(
    const unsigned short* __restrict__ xlr, const float* __restrict__ ea,
    const float* wb, const float (&att_r)[CPL], const float (&xr_r)[CPL],
    const int2* ep /*uniform*/, int c0,
    float& m, float& l, float (&acc)[CPL]) {
    int2 e[NE];
#pragma unroll
    for (int n = 0; n < NE; ++n) e[n] = ep[n];
    float ev[NE][8];
#pragma unroll
    for (int n = 0; n < NE; ++n) {
        float4 a = ((const float4*)(ea + (size_t)e[n].y * 8))[0];
        float4 b = ((const float4*)(ea + (size_t)e[n].y * 8))[1];
        ev[n][0] = a.x; ev[n][1] = a.y; ev[n][2] = a.z; ev[n][3] = a.w;
        ev[n][4] = b.x; ev[n][5] = b.y; ev[n][6] = b.z; ev[n][7] = b.w;
    }
    float xv[NE][CPL], z[NE][CPL];
#pragma unroll
    for (int n = 0; n < NE; ++n) {
        load_bf16v<CPL>(xlr + (size_t)e[n].x * (2 * D) + c0, xv[n]);
#pragma unroll
        for (int c = 0; c < CPL; ++c) z[n][c] = xv[n][c] + xr_r[c];
    }
#pragma unroll
    for (int k = 0; k < 8; ++k) {
#pragma unroll
        for (int q = 0; q < CPL / 4; ++q) {
            float4 w4 = *(const float4*)(wb + k * D + q * QP);
#pragma unroll
            for (int n = 0; n < NE; ++n) {
                z[n][q * 4 + 0] = fmaf(ev[n][k], w4.x, z[n][q * 4 + 0]);
                z[n][q * 4 + 1] = fmaf(ev[n][k], w4.y, z[n][q * 4 + 1]);
                z[n][q * 4 + 2] = fmaf(ev[n][k], w4.z, z[n][q * 4 + 2]);
                z[n][q * 4 + 3] = fmaf(ev[n][k], w4.w, z[n][q * 4 + 3]);
            }
        }
    }
    float lg[NE];
#pragma unroll
    for (int n = 0; n < NE; ++n) {
        lg[n] = 0.f;
#pragma unroll
        for (int c = 0; c < CPL; ++c) {
            float a = z[n][c] > 0.f ? z[n][c] : 0.2f * z[n][c];
            lg[n] = fmaf(att_r[c], a, lg[n]);
        }
        lg[n] = group_reduce<G>(lg[n]);
    }
    float mn = m;
#pragma unroll
    for (int n = 0; n < NE; ++n) mn = fmaxf(mn, lg[n]);
    float sc = __expf(m - mn);
    float p[NE], ps = 0.f;
#pragma unroll
    for (int n = 0; n < NE; ++n) { p[n] = __expf(lg[n] - mn); ps += p[n]; }
    m = mn;
    l = fmaf(l, sc, ps);
#pragma unroll
    for (int c = 0; c < CPL; ++c) {
        float t = p[0] * xv[0][c];
#pragma unroll
        for (int n = 1; n < NE; ++n) t = fmaf(p[n], xv[n][c], t);
        acc[c] = fmaf(acc[c], sc, t);
    }
}

template <int D, int C, int CB, int WPN, bool RELU>
__global__ __launch_bounds__(256) void attn_hase(
    const unsigned short* __restrict__ xlr, const float* __restrict__ ea,
    const float* __restrict__ We, const float* __restrict__ att,
    const int2* __restrict__ edges, const int* __restrict__ off,
    const float* __restrict__ bias, unsigned short* __restrict__ outp, int N) {
    constexpr int CPL = CB / 64;
    constexpr int HW = CB / C;
    constexpr int G = 64 / HW;
    constexpr int NPB = 4 / WPN;
    constexpr int QP = CB * 4 / CPL;
    __shared__ float wsh[8 * D];
    for (int f4 = threadIdx.x; f4 < 2 * D; f4 += 256) {
        int k = f4 / (D / 4);
        int c = (f4 - k * (D / 4)) * 4;
        int b = c / CB, cc = c - b * CB;
        int ln = cc / CPL, q = (cc % CPL) / 4;
        int dst = k * (D / 4) + (b * CB + q * QP + ln * 4) / 4;
        ((float4*)wsh)[dst] = ((const float4*)We)[f4];
    }
    __syncthreads();

    const int wid = threadIdx.x >> 6, lane = threadIdx.x & 63;
    const int wv = wid % WPN, wn = wid / WPN;
    const int c0 = wv * CB + lane * CPL;
    const float* wb = wsh + wv * CB + lane * 4;

    float att_r[CPL];
#pragma unroll
    for (int c = 0; c < CPL; ++c) att_r[c] = att[c0 + c];

    for (int node = blockIdx.x * NPB + wn; node < N; node += gridDim.x * NPB) {
        float xr_r[CPL];
        load_bf16v<CPL>(xlr + (size_t)node * (2 * D) + D + c0, xr_r);
        float m = -1e30f, l = 0.f, acc[CPL];
#pragma unroll
        for (int c = 0; c < CPL; ++c) acc[c] = 0.f;

        const int jb = __builtin_amdgcn_readfirstlane(off[node]);
        const int je = __builtin_amdgcn_readfirstlane(off[node + 1]);
        int j = jb;
        for (; j + 4 <= je; j += 4)
            hase_group<D, CPL, QP, G, 4>(xlr, ea, wb, att_r, xr_r, edges + j, c0, m, l, acc);
        for (; j < je; ++j)
            hase_group<D, CPL, QP, G, 1>(xlr, ea, wb, att_r, xr_r, edges + j, c0, m, l, acc);

        float inv = 1.f / (l + 1e-16f);
        float r[CPL];
#pragma unroll
        for (int c = 0; c < CPL; ++c) {
            r[c] = fmaf(acc[c], inv, bias[c0 + c]);
            if constexpr (RELU) r[c] = fmaxf(r[c], 0.f);
        }
        store_bf16v<CPL>(outp + (size_t)node * D + c0, r);
    }
}

// ---------- fused attention, no edge_attr (layer 3), NE groups ----------
template <int D, int CPL, int G, int NE>
static __device__ __forceinline__ void noe_group(
    const unsigned short* __restrict__ xlr,
    const float (&att_r)[CPL], const float (&xr_r)[CPL],
    const int2* ep /*uniform*/, int c0,
    float& m, float& l, float (&acc)[CPL]) {
    int2 e[NE];
#pragma unroll
    for (int n = 0; n < NE; ++n) e[n] = ep[n];
    float xv[NE][CPL], lg[NE];
#pragma unroll
    for (int n = 0; n < NE; ++n)
        load_bf16v<CPL>(xlr + (size_t)e[n].x * (2 * D) + c0, xv[n]);
#pragma unroll
    for (int n = 0; n < NE; ++n) {
        lg[n] = 0.f;
#pragma unroll
        for (int c = 0; c < CPL; ++c) {
            float z = xv[n][c] + xr_r[c];
            z = z > 0.f ? z : 0.2f * z;
            lg[n] = fmaf(att_r[c], z, lg[n]);
        }
        lg[n] = group_reduce<G>(lg[n]);
    }
    float mn = m;
#pragma unroll
    for (int n = 0; n < NE; ++n) mn = fmaxf(mn, lg[n]);
    float sc = __expf(m - mn);
    float p[NE], ps = 0.f;
#pragma unroll
    for (int n = 0; n < NE; ++n) { p[n] = __expf(lg[n] - mn); ps += p[n]; }
    m = mn;
    l = fmaf(l, sc, ps);
#pragma unroll
    for (int c = 0; c < CPL; ++c) {
        float t = p[0] * xv[0][c];
#pragma unroll
        for (int n = 1; n < NE; ++n) t = fmaf(p[n], xv[n][c], t);
        acc[c] = fmaf(acc[c], sc, t);
    }
}

template <int D, int C, int CB, bool RELU>
static __device__ __forceinline__ void attn_wave3(
    const unsigned short* __restrict__ xlr, const float* __restrict__ att,
    const int2* __restrict__ edges, int jb, int je,
    const float* __restrict__ bias, float* __restrict__ outp,
    int node, int cb, int lane) {
    constexpr int CPL = CB / 64;
    constexpr int HW = CB / C;
    constexpr int G = 64 / HW;
    const int c0 = cb + lane * CPL;

    float xr_r[CPL], att_r[CPL];
    load_bf16v<CPL>(xlr + (size_t)node * (2 * D) + D + c0, xr_r);
#pragma unroll
    for (int c = 0; c < CPL; ++c) att_r[c] = att[c0 + c];

    float m = -1e30f, l = 0.f, acc[CPL];
#pragma unroll
    for (int c = 0; c < CPL; ++c) acc[c] = 0.f;

    int j = jb;
    for (; j + 4 <= je; j += 4)
        noe_group<D, CPL, G, 4>(xlr, att_r, xr_r, edges + j, c0, m, l, acc);
    for (; j < je; ++j)
        noe_group<D, CPL, G, 1>(xlr, att_r, xr_r, edges + j, c0, m, l, acc);

    float inv = 1.f / (l + 1e-16f);
    float* out = outp + (size_t)node * D + c0;
    float tmp[CPL];
#pragma unroll
    for (int c = 0; c < CPL; ++c) {
        float r = fmaf(acc[c], inv, bias[c0 + c]);
        if constexpr (RELU) r = fmaxf(r, 0.f);
        tmp[c] = r;
    }
    if constexpr (CPL == 4) *(float4*)out = *(float4*)tmp;
    else if constexpr (CPL == 2) *(float2*)out = *(float2*)tmp;
    else out[0] = tmp[0];
}

template <int D, int C, int CB0, int CB1, bool RELU>
__global__ __launch_bounds__(256) void attn_noe(
    const unsigned short* __restrict__ xlr, const float* __restrict__ att,
    const int2* __restrict__ edges, const int* __restrict__ off,
    const float* __restrict__ bias, float* __restrict__ outp, int N) {
    const int wid = threadIdx.x >> 6, lane = threadIdx.x & 63;
    const int gw = blockIdx.x * 4 + wid;
    const int node = gw >> 1, wv = gw & 1;
    if (node >= N) return;
    const int jb = __builtin_amdgcn_readfirstlane(off[node]);
    const int je = __builtin_amdgcn_readfirstlane(off[node + 1]);
    if (wv == 0)
        attn_wave3<D, C, CB0, RELU>(xlr, att, edges, jb, je, bias, outp, node, 0, lane);
    else
        attn_wave3<D, C, CB1, RELU>(xlr, att, edges, jb, je, bias, outp, node, CB0, lane);
}

// ---------- head: 2-layer MLP on master (last) node of each graph ----------
__global__ void mlp_kernel(const float* __restrict__ h3, const int* __restrict__ nn,
                           const float* __restrict__ Wfc1, const float* __restrict__ bfc1,
                           const float* __restrict__ Wfc2, const float* __restrict__ bfc2,
                           float* __restrict__ out, int G) {
    int g = blockIdx.x, t = threadIdx.x;  // 64 threads
    int s = 0;
    for (int k = 0; k <= g; ++k) s += nn[k];
    const float* row = h3 + (size_t)(s - 1) * 384;
    float z = bfc1[t];
    for (int k = 0; k < 384; ++k) z = fmaf(row[k], Wfc1[k * 64 + t], z);
    z = fmaxf(z, 0.f);
    float v = z * Wfc2[t];
#pragma unroll
    for (int o = 32; o; o >>= 1) v += __shfl_xor(v, o, 64);
    if (t == 0) out[g] = v + bfc2[0];
}

extern "C" void kernel_launch(void* const* d_in, const int* in_sizes, int n_in,
                              void* d_out, int out_size, void* d_ws, size_t ws_size,
                              hipStream_t stream) {
    const float* x    = (const float*)d_in[0];
    const float* ea   = (const float*)d_in[1];
    const float* Wl1  = (const float*)d_in[2];
    const float* Wr1  = (const float*)d_in[3];
    const float* We1  = (const float*)d_in[4];
    const float* att1 = (const float*)d_in[5];
    const float* b1   = (const float*)d_in[6];
    const float* Wl2  = (const float*)d_in[7];
    const float* Wr2  = (const float*)d_in[8];
    const float* We2  = (const float*)d_in[9];
    const float* att2 = (const float*)d_in[10];
    const float* b2   = (const float*)d_in[11];
    const float* Wlp  = (const float*)d_in[12];
    const float* Wrp  = (const float*)d_in[13];
    const float* attp = (const float*)d_in[14];
    const float* bp   = (const float*)d_in[15];
    const float* Wfc1 = (const float*)d_in[16];
    const float* bfc1 = (const float*)d_in[17];
    const float* Wfc2 = (const float*)d_in[18];
    const float* bfc2 = (const float*)d_in[19];
    const int* ei     = (const int*)d_in[20];
    const int* eim    = (const int*)d_in[21];
    const int* nn     = (const int*)d_in[22];

    const int N = in_sizes[0] / 64;   // 20000
    const int E = in_sizes[20] / 2;   // 160000
    const int G = in_sizes[22];       // 100
    const int* src1 = ei,  *dst1 = ei + E;
    const int* srcm = eim, *dstm = eim + E;

    // ---- workspace layout (~160 MB peak) ----
    char* w = (char*)d_ws;
    size_t o = 0;
    auto alloc = [&](size_t b) { size_t r = o; o += (b + 255) & ~(size_t)255; return r; };
    char* R1 = w + alloc((size_t)N * 2048 * 2);
    unsigned short* xlr1 = (unsigned short*)R1;
    unsigned short* xlr3 = (unsigned short*)R1;
    float* h3 = (float*)(R1 + (size_t)N * 768 * 2 + 256);
    unsigned short* h1   = (unsigned short*)(w + alloc((size_t)N * 1024 * 2));
    unsigned short* xlr2 = (unsigned short*)(w + alloc((size_t)N * 512 * 2));
    unsigned short* h2   = (unsigned short*)(w + alloc((size_t)N * 256 * 2));
    unsigned short* xbf  = (unsigned short*)(w + alloc((size_t)N * 64 * 2));
    unsigned short* wt1  = (unsigned short*)(w + alloc((size_t)2048 * 64 * 2));
    unsigned short* wt2  = (unsigned short*)(w + alloc((size_t)512 * 1024 * 2));
    unsigned short* wt3  = (unsigned short*)(w + alloc((size_t)768 * 256 * 2));
    int*  cnt   = (int*)(w + alloc((size_t)2 * N * 4));
    int*  off   = (int*)(w + alloc((size_t)2 * (N + 1) * 4));
    int*  cur   = (int*)(w + alloc((size_t)2 * N * 4));
    int2* edges = (int2*)(w + alloc((size_t)2 * E * 8 + 4096));
    (void)ws_size; (void)n_in; (void)out_size;

    dim3 blk(256);

    // ---- weight prep (single merged launch) ----
    {
        int tot = 2 * 64 * 1024 + 2 * 1024 * 256 + 2 * 256 * 384 + N * 64;
        prep_all<<<DIV_UP(tot, 256), blk, 0, stream>>>(x, Wl1, Wr1, Wl2, Wr2, Wlp, Wrp,
                                                       xbf, wt1, wt2, wt3, N);
    }

    // ---- CSR for both graphs ----
    hipMemsetAsync(cnt, 0, (size_t)2 * N * 4, stream);
    count2_kernel<<<DIV_UP(2 * E, 256), blk, 0, stream>>>(dst1, dstm, E, N, cnt);
    scan_kernel<<<2, 1024, 0, stream>>>(cnt, N, off, cur);
    fill2_kernel<<<DIV_UP(2 * E, 256), blk, 0, stream>>>(src1, dst1, srcm, dstm, E, N, cur, edges);
    const int* off3 = off + (N + 1);
    int2* edges3 = edges + E;

    // ---- Layer 1: H=4, C=256, D=1024 — 2 waves/node, CPL=8, G=32, NE=4 ----
    gemm_mfma<<<dim3(2048 / 128, DIV_UP(N, 128)), blk, 0, stream>>>(xbf, wt1, xlr1, N, 2048, 64);
    attn_hase<1024, 256, 512, 2, true><<<2560, blk, 0, stream>>>(
        xlr1, ea, We1, att1, edges, off, b1, h1, N);

    // ---- Layer 2: H=4, C=64, D=256 — 1 wave/node, CPL=4, G=16, NE=4 ----
    gemm_mfma<<<dim3(512 / 128, DIV_UP(N, 128)), blk, 0, stream>>>(h1, wt2, xlr2, N, 512, 1024);
    attn_hase<256, 64, 256, 1, true><<<1280, blk, 0, stream>>>(
        xlr2, ea, We2, att2, edges, off, b2, h2, N);

    // ---- Layer 3: H=6, C=64, D=384 — 2 waves/node (roles 256/128), fp32 out, NE=4 ----
    gemm_mfma<<<dim3(768 / 128, DIV_UP(N, 128)), blk, 0, stream>>>(h2, wt3, xlr3, N, 768, 256);
    attn_noe<384, 64, 256, 128, false><<<DIV_UP(N, 2), blk, 0, stream>>>(
        xlr3, attp, edges3, off3, bp, h3, N);

    // ---- head ----
    mlp_kernel<<<G, 64, 0, stream>>>(h3, nn, Wfc1, bfc1, Wfc2, bfc2, (float*)d_out, G);
}